// Round 9
// baseline (654.417 us; speedup 1.0000x reference)
//
#include <hip/hip_runtime.h>
#include <cstdint>
#include <cstddef>

// ---------------------------------------------------------------------------
// SwitchBack int8 MLP: x -> rowquant -> i8GEMM(+bias+gelu) -> rowquant ->
//                      i8GEMM(+bias) -> out
// GEMM: 256x256 tile, BK=64, 8 waves, 3-buf LDS, ONE barrier per K-tile:
// ds_reads of tile T+1 interleaved under tile T's MFMA (reg WAR recycling),
// stage(T+3) 2-iter flight, lgkm0+vmcnt(4) once per tile. T2 swizzle,
// T5 setprio, XCD column-group mapping.
// mfma_i32_16x16x64_i8 == exact integer arithmetic == reference fp32 matmul.
// ---------------------------------------------------------------------------

typedef int v4i __attribute__((ext_vector_type(4)));

#define AS1 __attribute__((address_space(1)))
#define AS3 __attribute__((address_space(3)))

#define WAIT_LGKM(N) asm volatile("s_waitcnt lgkmcnt(" #N ")" ::: "memory")
#define WAIT_VM(N)   asm volatile("s_waitcnt vmcnt(" #N ")" ::: "memory")
#define SBAR() __builtin_amdgcn_s_barrier()
#define SFENCE() __builtin_amdgcn_sched_barrier(0)

__device__ __forceinline__ void gload_lds16(const void* g, void* l) {
    __builtin_amdgcn_global_load_lds((const AS1 void*)g, (AS3 void*)l, 16, 0, 0);
}

__device__ __forceinline__ float absmax4(float4 v, float cur) {
    return fmaxf(cur, fmaxf(fmaxf(fabsf(v.x), fabsf(v.y)),
                            fmaxf(fabsf(v.z), fabsf(v.w))));
}

__device__ __forceinline__ int quant1(float x, float inv) {
    int q = (int)rintf(x * inv);
    return min(127, max(-127, q));
}

__device__ __forceinline__ uint32_t quant4(float4 v, float inv) {
    uint32_t b0 = (uint32_t)(uint8_t)(int8_t)quant1(v.x, inv);
    uint32_t b1 = (uint32_t)(uint8_t)(int8_t)quant1(v.y, inv);
    uint32_t b2 = (uint32_t)(uint8_t)(int8_t)quant1(v.z, inv);
    uint32_t b3 = (uint32_t)(uint8_t)(int8_t)quant1(v.w, inv);
    return b0 | (b1 << 8) | (b2 << 16) | (b3 << 24);
}

// ---------------- global absmax of a big f32 array ----------------
__global__ __launch_bounds__(256) void wabs_kernel(
    const float* __restrict__ W, int n4, float* __restrict__ out)
{
    int tid = blockIdx.x * 256 + threadIdx.x;
    int stride = gridDim.x * 256;
    const float4* W4 = (const float4*)W;
    float amax = 0.0f;
    for (int i = tid; i < n4; i += stride) amax = absmax4(W4[i], amax);
    #pragma unroll
    for (int off = 32; off >= 1; off >>= 1)
        amax = fmaxf(amax, __shfl_xor(amax, off));
    __shared__ float red[4];
    if ((threadIdx.x & 63) == 0) red[threadIdx.x >> 6] = amax;
    __syncthreads();
    if (threadIdx.x == 0) {
        amax = fmaxf(fmaxf(red[0], red[1]), fmaxf(red[2], red[3]));
        atomicMax((int*)out, __float_as_int(amax));  // nonneg floats: int order ok
    }
}

// ---------------- quantize whole tensor with global scale ----------------
__global__ __launch_bounds__(256) void wquant_kernel(
    const float* __restrict__ W, int n4, const float* __restrict__ s,
    uint32_t* __restrict__ Wq)
{
    float inv = 127.0f / s[0];
    int tid = blockIdx.x * 256 + threadIdx.x;
    int stride = gridDim.x * 256;
    const float4* W4 = (const float4*)W;
    for (int i = tid; i < n4; i += stride) Wq[i] = quant4(W4[i], inv);
}

// ---------------- per-row absmax + quantize (one block per row) ----------------
template<int CNT>
__global__ __launch_bounds__(256) void rowquant_kernel(
    const float* __restrict__ X, int8_t* __restrict__ Xq,
    float* __restrict__ rowAbs)
{
    const int row = blockIdx.x;
    const int t = threadIdx.x;
    const size_t cols = (size_t)CNT * 1024;
    const float4* Xr = (const float4*)(X + (size_t)row * cols);
    float4 vals[CNT];
    float amax = 0.0f;
    #pragma unroll
    for (int j = 0; j < CNT; j++) {
        vals[j] = Xr[j * 256 + t];
        amax = absmax4(vals[j], amax);
    }
    #pragma unroll
    for (int off = 32; off >= 1; off >>= 1)
        amax = fmaxf(amax, __shfl_xor(amax, off));
    __shared__ float red[4];
    if ((t & 63) == 0) red[t >> 6] = amax;
    __syncthreads();
    amax = fmaxf(fmaxf(red[0], red[1]), fmaxf(red[2], red[3]));
    if (t == 0) rowAbs[row] = amax;
    float inv = 127.0f / amax;
    uint32_t* out = (uint32_t*)(Xq + (size_t)row * cols);
    #pragma unroll
    for (int j = 0; j < CNT; j++) out[j * 256 + t] = quant4(vals[j], inv);
}

// ---------------- int8 GEMM, 256x256 tile, BK=64, 1-barrier/K-tile ----------
// A: [M,K] i8 row-major, B: [Ncols,K] i8 row-major. C[m,n] = sum A[m,k]B[n,k].
// 512 threads = 8 waves (2 wr x 4 wc), each wave owns 128x64 of C.
// LDS 96KB: A [3][256][64], B [3][256][64]. Tile T lives in buf T%3.
// Swizzle: LDS row r, 16B-slot s holds global slot s^((r>>1)&3) (src-side).
// Per iter T: stage(T+3)->buf T%3; MFMA(tile T, in regs) with tile T+1's
// ds_reads interleaved (a[m] recycled after last use); lgkm0+vmcnt(4)+bar.
// Buffer safety: all reads of buf b drain at iter (tile b's) lgkm0+barrier,
// one full iter before any stage overwrites b. Stage flight = 2 iters.
template<int GELU>
__global__ __launch_bounds__(512, 2) void gemm8_i8(
    const int8_t* __restrict__ A, const int8_t* __restrict__ B,
    int K, int Ncols, int cs,
    const float* __restrict__ rowScale, const float* __restrict__ wScale,
    const float* __restrict__ bias, float* __restrict__ Cout)
{
    extern __shared__ int8_t lds[];
    int8_t* AsB = lds;             // [3][256][64] = 48KB
    int8_t* BsB = lds + 49152;     // [3][256][64] = 48KB

    // XCD column-group mapping: XCD c owns bx in [c*cpx, (c+1)*cpx);
    // consecutive co-XCD blocks share by (A-panel) and keep B-group L2-hot.
    // Requires gridDim.x % 8 == 0 and nbx == 8<<cs.
    const int bid = blockIdx.x;
    const int c = bid & 7;
    const int i = bid >> 3;
    const int cpx = 1 << cs;
    const int bx = c * cpx + (i & (cpx - 1));
    const int by = i >> cs;
    const int brow = by * 256;
    const int bcol = bx * 256;

    const int t = threadIdx.x;
    const int lane = t & 63;
    const int w = t >> 6;          // wave 0..7
    const int wr = w >> 2;         // 0..1 (A rows 128*wr)
    const int wc = w & 3;          // 0..3 (B rows 64*wc)
    const int llo = lane & 15;
    const int lhi = lane >> 4;     // k-slot 0..3

    const int8_t* gA = A + (size_t)brow * K;
    const int8_t* gB = B + (size_t)bcol * K;

    // staging: thread t writes LDS bytes [t*16,+16) (row t>>2, slot t&3) and
    // [+8192] (row +128). Source slot pre-swizzled: (t&3)^((t>>3)&3).
    const size_t srcOffBase = (size_t)(t >> 2) * K
                            + (size_t)(((t & 3) ^ ((t >> 3) & 3)) * 16);
    const int ldsDst = t * 16;

    // reader: fragment row r = base+m*16+llo; k-slot lhi -> LDS slot
    // lhi^((r>>1)&3) = lhi^((llo>>1)&3) (lane-constant byte offset).
    const int sA = ((lhi ^ ((llo >> 1) & 3)) << 4);
    const int aOff = (wr * 128 + llo) * 64 + sA;
    const int bOff = (wc * 64 + llo) * 64 + sA;

    const int NT = K >> 6;

    v4i acc[8][4] = {};

    auto stageA = [&](int tile, int r) {
        const size_t gb = (size_t)tile * 64 + srcOffBase;
        int8_t* d = AsB + r * 16384 + ldsDst;
        gload_lds16(gA + gb, d);
        gload_lds16(gA + gb + (size_t)128 * K, d + 8192);
    };
    auto stageB = [&](int tile, int r) {
        const size_t gb = (size_t)tile * 64 + srcOffBase;
        int8_t* d = BsB + r * 16384 + ldsDst;
        gload_lds16(gB + gb, d);
        gload_lds16(gB + gb + (size_t)128 * K, d + 8192);
    };

    // prologue: stage tiles 0,1,2 into bufs 0,1,2; drain 0,1 (keep 2 in flight)
    stageA(0, 0); stageB(0, 0); stageA(1, 1); stageB(1, 1); stageA(2, 2); stageB(2, 2);
    WAIT_VM(4);
    SFENCE();
    SBAR();

    v4i a[8], b[4];
    #pragma unroll
    for (int m = 0; m < 8; m++) a[m] = *(const v4i*)(AsB + aOff + m * 1024);
    #pragma unroll
    for (int n = 0; n < 4; n++) b[n] = *(const v4i*)(BsB + bOff + n * 1024);
    WAIT_LGKM(0);
    SFENCE();
    SBAR();   // all waves done reading tile 0 (buf 0) before iter0 stages it

    int rT = 0;  // T % 3
    for (int T = 0; T < NT; ++T) {
        if (T + 3 < NT) { stageA(T + 3, rT); stageB(T + 3, rT); }
        const int rn = (rT + 1 < 3) ? rT + 1 : 0;
        const int rb = (T + 1 < NT) ? rn : rT;   // tail: re-read last tile
        const int8_t* Ab = AsB + rb * 16384;
        const int8_t* Bb = BsB + rb * 16384;

        #pragma unroll
        for (int m = 0; m < 8; m++) {
            __builtin_amdgcn_s_setprio(1);
            #pragma unroll
            for (int n = 0; n < 4; n++)
                acc[m][n] = __builtin_amdgcn_mfma_i32_16x16x64_i8(
                    a[m], b[n], acc[m][n], 0, 0, 0);
            __builtin_amdgcn_s_setprio(0);
            a[m] = *(const v4i*)(Ab + aOff + m * 1024);   // tile T+1, reg WAR
        }
        #pragma unroll
        for (int n = 0; n < 4; n++) b[n] = *(const v4i*)(Bb + bOff + n * 1024);

        WAIT_LGKM(0);   // tile T+1 frags ready; all own reads of buf done
        WAIT_VM(4);     // tile T+2 resident (stage T+3 stays in flight)
        SFENCE();
        SBAR();         // all waves done -> buf rT safe to overwrite next iter
        rT = rn;
    }

    // epilogue: C/D layout col=lane&15, row=(lane>>4)*4+reg
    const float wsc = wScale[0] * (1.0f / (127.0f * 127.0f));
    #pragma unroll
    for (int m = 0; m < 8; m++) {
        #pragma unroll
        for (int r4 = 0; r4 < 4; r4++) {
            const int row = brow + wr * 128 + m * 16 + lhi * 4 + r4;
            const float s = rowScale[row] * wsc;
            #pragma unroll
            for (int n = 0; n < 4; n++) {
                const int col = bcol + wc * 64 + n * 16 + llo;
                float v = (float)acc[m][n][r4] * s + bias[col];
                if (GELU) {
                    float u = v + 0.044715f * v * v * v;
                    v = v / (1.0f + __expf(-1.5957691216057308f * u));
                }
                Cout[(size_t)row * Ncols + col] = v;
            }
        }
    }
}

// ---------------------------------------------------------------------------
extern "C" void kernel_launch(void* const* d_in, const int* in_sizes, int n_in,
                              void* d_out, int out_size, void* d_ws, size_t ws_size,
                              hipStream_t stream)
{
    const float* x  = (const float*)d_in[0];   // [8192,2048]
    const float* W1 = (const float*)d_in[1];   // [8192,2048]
    const float* B1 = (const float*)d_in[2];   // [8192]
    const float* W2 = (const float*)d_in[3];   // [2048,8192]
    const float* B2 = (const float*)d_in[4];   // [2048]
    float* out = (float*)d_out;                // [8192,2048]

    const int N = 8192, D = 2048, H = 8192;
    const size_t MB = 1024 * 1024;

    // 96KB dynamic LDS opt-in (host-side attribute set; not a stream op)
    hipFuncSetAttribute((const void*)gemm8_i8<1>,
                        hipFuncAttributeMaxDynamicSharedMemorySize, 98304);
    hipFuncSetAttribute((const void*)gemm8_i8<0>,
                        hipFuncAttributeMaxDynamicSharedMemorySize, 98304);

    // workspace layout (adaptive):
    //   0..64KB+: scales; 1MB: X1q 16MB (aliased by W2q later); 17MB: W1q 16MB;
    //   33MB: X2q 64MB; 97MB: X2f chunk staging (chunk*H*4 bytes)
    char* ws = (char*)d_ws;
    float* sW1 = (float*)(ws + 0);
    float* sW2 = (float*)(ws + 4);
    float* sX1 = (float*)(ws + 256);
    float* sX2 = (float*)(ws + 256 + 32768);
    size_t off = 1 * MB;
    int8_t* X1q = (int8_t*)(ws + off);
    int8_t* W2q = X1q;                 // alias: W2q written after X1q is dead
    off += (size_t)N * D;
    int8_t* W1q = (int8_t*)(ws + off); off += (size_t)H * D;
    int8_t* X2q = (int8_t*)(ws + off); off += (size_t)N * H;
    float*  X2f = (float*)(ws + off);
    const size_t fixedBytes = off;

    // largest chunk (multiple of 256 rows) whose f32 staging fits
    int chunk = N;
    if (ws_size < fixedBytes + (size_t)N * H * 4) {
        size_t avail = ws_size > fixedBytes ? ws_size - fixedBytes : 0;
        size_t c = avail / ((size_t)H * 4);
        c = (c / 256) * 256;
        if (c < 256) c = 256;
        if (c > (size_t)N) c = N;
        chunk = (int)c;
    }

    hipMemsetAsync(d_ws, 0, 256 + 65536, stream);

    wabs_kernel<<<2048, 256, 0, stream>>>(W1, H * D / 4, sW1);
    wquant_kernel<<<4096, 256, 0, stream>>>(W1, H * D / 4, sW1, (uint32_t*)W1q);
    rowquant_kernel<2><<<N, 256, 0, stream>>>(x, X1q, sX1);

    for (int r0 = 0; r0 < N; r0 += chunk) {
        const int rows = min(chunk, N - r0);
        // nbx = H/256 = 32 = 8<<2 -> cs = 2
        gemm8_i8<1><<<(H / 256) * (rows / 256), 512, 98304, stream>>>(
            X1q + (size_t)r0 * D, W1q, D, H, 2,
            sX1 + r0, sW1, B1, X2f);
        rowquant_kernel<8><<<rows, 256, 0, stream>>>(
            X2f, X2q + (size_t)r0 * H, sX2 + r0);
    }

    wabs_kernel<<<2048, 256, 0, stream>>>(W2, D * H / 4, sW2);
    wquant_kernel<<<4096, 256, 0, stream>>>(W2, D * H / 4, sW2, (uint32_t*)W2q);

    // nbx = D/256 = 8 = 8<<0 -> cs = 0
    gemm8_i8<0><<<(D / 256) * (N / 256), 512, 98304, stream>>>(
        X2q, W2q, H, D, 0, sX2, sW2, B2, out);
}

// Round 10
// 648.087 us; speedup vs baseline: 1.0098x; 1.0098x over previous
//
#include <hip/hip_runtime.h>
#include <cstdint>
#include <cstddef>

// ---------------------------------------------------------------------------
// SwitchBack int8 MLP: x -> rowquant -> i8GEMM(+bias+gelu) -> rowquant ->
//                      i8GEMM(+bias) -> out
// GEMM: 256x256 tile, BK=64, 8 waves, 3-buf LDS, 1 barrier/tile, ALL 12
// ds_reads spread across MFMA quads via b-fragment double-buffering (no
// end-of-tile LDS burst). nt-stores for streaming outputs (C/X2f) to stop
// L2/L3 write-thrash. T2 swizzle, T5 setprio, contiguous-XCD block mapping.
// mfma_i32_16x16x64_i8 == exact integer arithmetic == reference fp32 matmul.
// ---------------------------------------------------------------------------

typedef int v4i __attribute__((ext_vector_type(4)));
typedef float v4f __attribute__((ext_vector_type(4)));

#define AS1 __attribute__((address_space(1)))
#define AS3 __attribute__((address_space(3)))

#define WAIT_LGKM(N) asm volatile("s_waitcnt lgkmcnt(" #N ")" ::: "memory")
#define WAIT_VM(N)   asm volatile("s_waitcnt vmcnt(" #N ")" ::: "memory")
#define SBAR() __builtin_amdgcn_s_barrier()
#define SFENCE() __builtin_amdgcn_sched_barrier(0)

__device__ __forceinline__ void gload_lds16(const void* g, void* l) {
    __builtin_amdgcn_global_load_lds((const AS1 void*)g, (AS3 void*)l, 16, 0, 0);
}

__device__ __forceinline__ float absmax4(v4f v, float cur) {
    return fmaxf(cur, fmaxf(fmaxf(fabsf(v[0]), fabsf(v[1])),
                            fmaxf(fabsf(v[2]), fabsf(v[3]))));
}

__device__ __forceinline__ int quant1(float x, float inv) {
    int q = (int)rintf(x * inv);
    return min(127, max(-127, q));
}

__device__ __forceinline__ uint32_t quant4(v4f v, float inv) {
    uint32_t b0 = (uint32_t)(uint8_t)(int8_t)quant1(v[0], inv);
    uint32_t b1 = (uint32_t)(uint8_t)(int8_t)quant1(v[1], inv);
    uint32_t b2 = (uint32_t)(uint8_t)(int8_t)quant1(v[2], inv);
    uint32_t b3 = (uint32_t)(uint8_t)(int8_t)quant1(v[3], inv);
    return b0 | (b1 << 8) | (b2 << 16) | (b3 << 24);
}

// ---------------- global absmax of a big f32 array ----------------
__global__ __launch_bounds__(256) void wabs_kernel(
    const float* __restrict__ W, int n4, float* __restrict__ out)
{
    int tid = blockIdx.x * 256 + threadIdx.x;
    int stride = gridDim.x * 256;
    const v4f* W4 = (const v4f*)W;
    float amax = 0.0f;
    for (int i = tid; i < n4; i += stride) amax = absmax4(W4[i], amax);
    #pragma unroll
    for (int off = 32; off >= 1; off >>= 1)
        amax = fmaxf(amax, __shfl_xor(amax, off));
    __shared__ float red[4];
    if ((threadIdx.x & 63) == 0) red[threadIdx.x >> 6] = amax;
    __syncthreads();
    if (threadIdx.x == 0) {
        amax = fmaxf(fmaxf(red[0], red[1]), fmaxf(red[2], red[3]));
        atomicMax((int*)out, __float_as_int(amax));  // nonneg floats: int order ok
    }
}

// ---------------- quantize whole tensor with global scale ----------------
__global__ __launch_bounds__(256) void wquant_kernel(
    const float* __restrict__ W, int n4, const float* __restrict__ s,
    uint32_t* __restrict__ Wq)
{
    float inv = 127.0f / s[0];
    int tid = blockIdx.x * 256 + threadIdx.x;
    int stride = gridDim.x * 256;
    const v4f* W4 = (const v4f*)W;
    for (int i = tid; i < n4; i += stride) Wq[i] = quant4(W4[i], inv);
}

// ---------------- per-row absmax + quantize (one block per row) ----------------
// input is a read-once stream -> nontemporal loads (don't pollute L2/L3)
template<int CNT>
__global__ __launch_bounds__(256) void rowquant_kernel(
    const float* __restrict__ X, int8_t* __restrict__ Xq,
    float* __restrict__ rowAbs)
{
    const int row = blockIdx.x;
    const int t = threadIdx.x;
    const size_t cols = (size_t)CNT * 1024;
    const v4f* Xr = (const v4f*)(X + (size_t)row * cols);
    v4f vals[CNT];
    float amax = 0.0f;
    #pragma unroll
    for (int j = 0; j < CNT; j++) {
        vals[j] = __builtin_nontemporal_load(&Xr[j * 256 + t]);
        amax = absmax4(vals[j], amax);
    }
    #pragma unroll
    for (int off = 32; off >= 1; off >>= 1)
        amax = fmaxf(amax, __shfl_xor(amax, off));
    __shared__ float red[4];
    if ((t & 63) == 0) red[t >> 6] = amax;
    __syncthreads();
    amax = fmaxf(fmaxf(red[0], red[1]), fmaxf(red[2], red[3]));
    if (t == 0) rowAbs[row] = amax;
    float inv = 127.0f / amax;
    uint32_t* out = (uint32_t*)(Xq + (size_t)row * cols);
    #pragma unroll
    for (int j = 0; j < CNT; j++) out[j * 256 + t] = quant4(vals[j], inv);
}

// ---------------- int8 GEMM, 256x256 tile, BK=64, spread-read pipeline ------
// A: [M,K] i8 row-major, B: [Ncols,K] i8 row-major. C[m,n] = sum A[m,k]B[n,k].
// 512 threads = 8 waves (2 wr x 4 wc), each wave owns 128x64 of C.
// LDS 96KB: A [3][256][64], B [3][256][64]. Tile T lives in buf T%3.
// Swizzle: LDS row r, slot s holds global slot s^((r>>1)&3) (src-side, m173).
// Iter T: regs hold tile T (a[8], bc[4]); buf (T+1)%3 holds tile T+1.
//   quad m (4 MFMA) -> reload a[m] (+ bn[m] for m<4) from buf (T+1)%3.
//   stage(T+3)->buf T%3 issued after quad 0 (hidden under MFMA).
//   End: lgkm0 (reads long done) + vmcnt(4) (tile T+2 resident) + 1 barrier.
// b-fragments double-buffered (bc/bn) so no read waits until after its quad.
template<int GELU>
__global__ __launch_bounds__(512, 2) void gemm8_i8(
    const int8_t* __restrict__ A, const int8_t* __restrict__ B,
    int K, int Ncols, int nbx,
    const float* __restrict__ rowScale, const float* __restrict__ wScale,
    const float* __restrict__ bias, float* __restrict__ Cout)
{
    extern __shared__ int8_t lds[];
    int8_t* AsB = lds;             // [3][256][64] = 48KB
    int8_t* BsB = lds + 49152;     // [3][256][64] = 48KB

    // contiguous-XCD mapping (round-8 measured-good): XCD c gets a contiguous
    // wg range -> co-resident blocks share by-panels (A) and L3 holds B.
    const int nwg = gridDim.x;
    const int bid = blockIdx.x;
    const int wg = (bid & 7) * (nwg >> 3) + (bid >> 3);
    const int bx = wg % nbx;
    const int by = wg / nbx;
    const int brow = by * 256;
    const int bcol = bx * 256;

    const int t = threadIdx.x;
    const int lane = t & 63;
    const int w = t >> 6;          // wave 0..7
    const int wr = w >> 2;         // 0..1 (A rows 128*wr)
    const int wc = w & 3;          // 0..3 (B rows 64*wc)
    const int llo = lane & 15;
    const int lhi = lane >> 4;     // k-slot 0..3

    const int8_t* gA = A + (size_t)brow * K;
    const int8_t* gB = B + (size_t)bcol * K;

    // staging: thread t writes LDS bytes [t*16,+16) (row t>>2, slot t&3) and
    // [+8192] (row +128). Source slot pre-swizzled: (t&3)^((t>>3)&3).
    const size_t srcOffBase = (size_t)(t >> 2) * K
                            + (size_t)(((t & 3) ^ ((t >> 3) & 3)) * 16);
    const int ldsDst = t * 16;

    // reader: fragment row r = base+m*16+llo; k-slot lhi -> LDS slot
    // lhi^((r>>1)&3) = lhi^((llo>>1)&3) (lane-constant byte offset).
    const int sA = ((lhi ^ ((llo >> 1) & 3)) << 4);
    const int aOff = (wr * 128 + llo) * 64 + sA;
    const int bOff = (wc * 64 + llo) * 64 + sA;

    const int NT = K >> 6;

    v4i acc[8][4] = {};

    auto stageA = [&](int tile, int r) {
        const size_t gb = (size_t)tile * 64 + srcOffBase;
        int8_t* d = AsB + r * 16384 + ldsDst;
        gload_lds16(gA + gb, d);
        gload_lds16(gA + gb + (size_t)128 * K, d + 8192);
    };
    auto stageB = [&](int tile, int r) {
        const size_t gb = (size_t)tile * 64 + srcOffBase;
        int8_t* d = BsB + r * 16384 + ldsDst;
        gload_lds16(gB + gb, d);
        gload_lds16(gB + gb + (size_t)128 * K, d + 8192);
    };

    // prologue: tiles 0,1,2 -> bufs 0,1,2; drain tiles 0,1 (leave 4 in flight)
    stageA(0, 0); stageB(0, 0); stageA(1, 1); stageB(1, 1); stageA(2, 2); stageB(2, 2);
    WAIT_VM(4);
    SFENCE();
    SBAR();

    v4i a[8], bc[4], bn[4];
    #pragma unroll
    for (int m = 0; m < 8; m++) a[m] = *(const v4i*)(AsB + aOff + m * 1024);
    #pragma unroll
    for (int n = 0; n < 4; n++) bc[n] = *(const v4i*)(BsB + bOff + n * 1024);
    WAIT_LGKM(0);
    SFENCE();
    SBAR();   // all waves done reading buf0 before iter0 stages into it

    #define QUAD(MM, BV)                                                     \
        __builtin_amdgcn_s_setprio(1);                                       \
        _Pragma("unroll")                                                    \
        for (int n = 0; n < 4; n++)                                          \
            acc[MM][n] = __builtin_amdgcn_mfma_i32_16x16x64_i8(              \
                a[MM], BV[n], acc[MM][n], 0, 0, 0);                          \
        __builtin_amdgcn_s_setprio(0);

    // one K-tile: consume (a, BC) = tile T_; refill a,BN_ from tile T_+1
    #define ITER(BC, BN_, T_) {                                              \
        const int ts = ((T_) + 3 < NT) ? (T_) + 3 : NT - 1;                  \
        const int rS = (T_) % 3;                                             \
        const int rb = (((T_) + 1 < NT) ? (T_) + 1 : NT - 1) % 3;            \
        const int8_t* Ab = AsB + rb * 16384;                                 \
        const int8_t* Bb = BsB + rb * 16384;                                 \
        QUAD(0, BC)                                                          \
        if ((T_) + 3 < NT) { stageA(ts, rS); stageB(ts, rS); }               \
        a[0] = *(const v4i*)(Ab + aOff);                                     \
        BN_[0] = *(const v4i*)(Bb + bOff);                                   \
        QUAD(1, BC) a[1] = *(const v4i*)(Ab + aOff + 1024);                  \
        BN_[1] = *(const v4i*)(Bb + bOff + 1024);                            \
        QUAD(2, BC) a[2] = *(const v4i*)(Ab + aOff + 2048);                  \
        BN_[2] = *(const v4i*)(Bb + bOff + 2048);                            \
        QUAD(3, BC) a[3] = *(const v4i*)(Ab + aOff + 3072);                  \
        BN_[3] = *(const v4i*)(Bb + bOff + 3072);                            \
        QUAD(4, BC) a[4] = *(const v4i*)(Ab + aOff + 4096);                  \
        QUAD(5, BC) a[5] = *(const v4i*)(Ab + aOff + 5120);                  \
        QUAD(6, BC) a[6] = *(const v4i*)(Ab + aOff + 6144);                  \
        QUAD(7, BC) a[7] = *(const v4i*)(Ab + aOff + 7168);                  \
        WAIT_LGKM(0);                                                        \
        if ((T_) + 3 < NT) { WAIT_VM(4); } else { WAIT_VM(0); }              \
        SFENCE();                                                            \
        SBAR();                                                              \
    }

    for (int T = 0; T < NT; T += 2) {   // NT even (K multiple of 128)
        ITER(bc, bn, T)
        ITER(bn, bc, T + 1)
    }
    #undef ITER
    #undef QUAD

    // epilogue: C/D layout col=lane&15, row=(lane>>4)*4+reg; nt stores
    // (C / X2f are streaming write-once outputs -> don't thrash L2/L3)
    const float wsc = wScale[0] * (1.0f / (127.0f * 127.0f));
    #pragma unroll
    for (int m = 0; m < 8; m++) {
        #pragma unroll
        for (int r4 = 0; r4 < 4; r4++) {
            const int row = brow + wr * 128 + m * 16 + lhi * 4 + r4;
            const float s = rowScale[row] * wsc;
            #pragma unroll
            for (int n = 0; n < 4; n++) {
                const int col = bcol + wc * 64 + n * 16 + llo;
                float v = (float)acc[m][n][r4] * s + bias[col];
                if (GELU) {
                    float u = v + 0.044715f * v * v * v;
                    v = v / (1.0f + __expf(-1.5957691216057308f * u));
                }
                __builtin_nontemporal_store(v, &Cout[(size_t)row * Ncols + col]);
            }
        }
    }
}

// ---------------------------------------------------------------------------
extern "C" void kernel_launch(void* const* d_in, const int* in_sizes, int n_in,
                              void* d_out, int out_size, void* d_ws, size_t ws_size,
                              hipStream_t stream)
{
    const float* x  = (const float*)d_in[0];   // [8192,2048]
    const float* W1 = (const float*)d_in[1];   // [8192,2048]
    const float* B1 = (const float*)d_in[2];   // [8192]
    const float* W2 = (const float*)d_in[3];   // [2048,8192]
    const float* B2 = (const float*)d_in[4];   // [2048]
    float* out = (float*)d_out;                // [8192,2048]

    const int N = 8192, D = 2048, H = 8192;
    const size_t MB = 1024 * 1024;

    // 96KB dynamic LDS opt-in (host-side attribute set; not a stream op)
    hipFuncSetAttribute((const void*)gemm8_i8<1>,
                        hipFuncAttributeMaxDynamicSharedMemorySize, 98304);
    hipFuncSetAttribute((const void*)gemm8_i8<0>,
                        hipFuncAttributeMaxDynamicSharedMemorySize, 98304);

    // workspace layout (adaptive):
    //   0..64KB+: scales; 1MB: X1q 16MB (aliased by W2q later); 17MB: W1q 16MB;
    //   33MB: X2q 64MB; 97MB: X2f chunk staging (chunk*H*4 bytes)
    char* ws = (char*)d_ws;
    float* sW1 = (float*)(ws + 0);
    float* sW2 = (float*)(ws + 4);
    float* sX1 = (float*)(ws + 256);
    float* sX2 = (float*)(ws + 256 + 32768);
    size_t off = 1 * MB;
    int8_t* X1q = (int8_t*)(ws + off);
    int8_t* W2q = X1q;                 // alias: W2q written after X1q is dead
    off += (size_t)N * D;
    int8_t* W1q = (int8_t*)(ws + off); off += (size_t)H * D;
    int8_t* X2q = (int8_t*)(ws + off); off += (size_t)N * H;
    float*  X2f = (float*)(ws + off);
    const size_t fixedBytes = off;

    // largest chunk (multiple of 256 rows) whose f32 staging fits
    int chunk = N;
    if (ws_size < fixedBytes + (size_t)N * H * 4) {
        size_t avail = ws_size > fixedBytes ? ws_size - fixedBytes : 0;
        size_t c = avail / ((size_t)H * 4);
        c = (c / 256) * 256;
        if (c < 256) c = 256;
        if (c > (size_t)N) c = N;
        chunk = (int)c;
    }

    hipMemsetAsync(d_ws, 0, 256 + 65536, stream);

    wabs_kernel<<<2048, 256, 0, stream>>>(W1, H * D / 4, sW1);
    wquant_kernel<<<4096, 256, 0, stream>>>(W1, H * D / 4, sW1, (uint32_t*)W1q);
    rowquant_kernel<2><<<N, 256, 0, stream>>>(x, X1q, sX1);

    for (int r0 = 0; r0 < N; r0 += chunk) {
        const int rows = min(chunk, N - r0);
        gemm8_i8<1><<<(H / 256) * (rows / 256), 512, 98304, stream>>>(
            X1q + (size_t)r0 * D, W1q, D, H, H / 256,
            sX1 + r0, sW1, B1, X2f);
        rowquant_kernel<8><<<rows, 256, 0, stream>>>(
            X2f, X2q + (size_t)r0 * H, sX2 + r0);
    }

    wabs_kernel<<<2048, 256, 0, stream>>>(W2, D * H / 4, sW2);
    wquant_kernel<<<4096, 256, 0, stream>>>(W2, D * H / 4, sW2, (uint32_t*)W2q);

    gemm8_i8<0><<<(D / 256) * (N / 256), 512, 98304, stream>>>(
        X2q, W2q, H, D, D / 256, sX2, sW2, B2, out);
}